// Round 2
// baseline (183.069 us; speedup 1.0000x reference)
//
#include <hip/hip_runtime.h>

// VanillaGNN: B=262144 graphs, N=8 nodes, DIN=3, DH=32, DOUT=1, E=32 shared edges.
// Per-graph:  h1 = relu((A@x)@W1 + b1); h2 = relu(A@(h1@W2) + b2);
//             out = mean_n relu(h2@Wout + bout)
// Layout: 256 threads/block = 8 graphs x 32 threads. Thread (g, j) owns hidden
// column j of all 8 nodes of graph g. Node-mixing (A@) is register-local per
// column; only the 32x32 GEMM crosses columns -> stage h1 in LDS.
// NOTE: harness delivers integer inputs as int32 (not int64) — cast ei to int*.

#define GPB 8  // graphs per block

__global__ __launch_bounds__(256) void gnn_kernel(
    const float* __restrict__ x,       // [B,8,3]
    const int* __restrict__ ei,        // [2,32] int32
    const float* __restrict__ W1,      // [3,32]
    const float* __restrict__ b1,      // [32]
    const float* __restrict__ W2,      // [32,32]
    const float* __restrict__ b2,      // [32]
    const float* __restrict__ Wout,    // [32]
    const float* __restrict__ bout,    // [1]
    float* __restrict__ out,           // [B]
    int B)
{
    __shared__ float As[64];     // A[n][m]  (n=dst, m=src)
    __shared__ float ATs[64];    // A^T[m][n] (for float4 over n)
    __shared__ float degs[8];
    __shared__ float dinvs[8];
    __shared__ float W1s[96];    // W1[d][j]
    __shared__ float b1s[32];
    __shared__ float W2s[1024];  // W2[k][j]
    __shared__ float b2s[32];
    __shared__ float Wouts[32];
    __shared__ float xs[192];    // [g][8][3]
    __shared__ float ys[192];    // (A@x) [g][8][3]
    __shared__ float h1s[GPB * 260];  // [g][n][32], per-graph stride 260 (pad)

    const int tid = threadIdx.x;
    const long long gbase = (long long)blockIdx.x * GPB;

    // ---- stage constants / inputs ----
    if (tid < 96) W1s[tid] = W1[tid];
    if (tid < 64) As[tid] = 0.0f;
    if (tid < 32) { b1s[tid] = b1[tid]; b2s[tid] = b2[tid]; Wouts[tid] = Wout[tid]; }
    if (tid < 8)  degs[tid] = 1.0f;  // self loop
    for (int i = tid; i < 1024; i += 256) W2s[i] = W2[i];
    if (tid < 192) {
        long long xi = gbase * 24 + tid;
        xs[tid] = (xi < (long long)B * 24) ? x[xi] : 0.0f;
    }
    __syncthreads();

    // ---- build normalized adjacency A (shared across all graphs) ----
    if (tid < 32) { int d = ei[32 + tid]; atomicAdd(&degs[d], 1.0f); }
    __syncthreads();
    if (tid < 8) dinvs[tid] = 1.0f / sqrtf(degs[tid]);
    __syncthreads();
    if (tid < 32) {
        int s = ei[tid], d = ei[32 + tid];
        atomicAdd(&As[d * 8 + s], dinvs[s] * dinvs[d]);
    } else if (tid < 40) {
        int n = tid - 32;
        atomicAdd(&As[n * 8 + n], dinvs[n] * dinvs[n]);
    }
    __syncthreads();
    if (tid < 64) ATs[(tid & 7) * 8 + (tid >> 3)] = As[tid];
    __syncthreads();

    // ---- y = A @ x  (192 values, one per thread) ----
    if (tid < 192) {
        int g = tid / 24, r = tid % 24, n = r / 3, dd = r % 3;
        float acc = 0.0f;
        #pragma unroll
        for (int m = 0; m < 8; m++) acc += As[n * 8 + m] * xs[g * 24 + m * 3 + dd];
        ys[tid] = acc;
    }
    __syncthreads();

    const int g = tid >> 5;   // local graph 0..7
    const int j = tid & 31;   // hidden column 0..31
    float* hb = &h1s[g * 260];

    // ---- layer 1: h1[n] = relu(y[n] @ W1[:,j] + b1[j]) ----
    const float w1a = W1s[j], w1b = W1s[32 + j], w1c = W1s[64 + j], b1j = b1s[j];
    float h1[8];
    #pragma unroll
    for (int n = 0; n < 8; n++) {
        const float* yr = &ys[g * 24 + n * 3];
        h1[n] = fmaxf(fmaf(yr[0], w1a, fmaf(yr[1], w1b, fmaf(yr[2], w1c, b1j))), 0.0f);
    }
    #pragma unroll
    for (int n = 0; n < 8; n++) hb[n * 32 + j] = h1[n];

    // preload W2 column j into registers (reused 8x)
    float w2k[32];
    #pragma unroll
    for (int k = 0; k < 32; k++) w2k[k] = W2s[k * 32 + j];
    const float boutv = bout[0];
    __syncthreads();

    // ---- layer 2 GEMM: t[n] = h1[n,:] @ W2[:,j] ----
    float t[8];
    #pragma unroll
    for (int n = 0; n < 8; n++) {
        float acc = 0.0f;
        #pragma unroll
        for (int k4 = 0; k4 < 8; k4++) {
            float4 gv = *reinterpret_cast<const float4*>(&hb[n * 32 + k4 * 4]);
            acc = fmaf(gv.x, w2k[4 * k4 + 0], acc);
            acc = fmaf(gv.y, w2k[4 * k4 + 1], acc);
            acc = fmaf(gv.z, w2k[4 * k4 + 2], acc);
            acc = fmaf(gv.w, w2k[4 * k4 + 3], acc);
        }
        t[n] = acc;
    }

    // ---- aggregate: h2[n] = relu(sum_m A[n][m] t[m] + b2[j]) ----
    float h2[8];
    #pragma unroll
    for (int n = 0; n < 8; n++) h2[n] = 0.0f;
    #pragma unroll
    for (int m = 0; m < 8; m++) {
        float4 alo = *reinterpret_cast<const float4*>(&ATs[m * 8]);
        float4 ahi = *reinterpret_cast<const float4*>(&ATs[m * 8 + 4]);
        const float hm = t[m];
        h2[0] = fmaf(alo.x, hm, h2[0]); h2[1] = fmaf(alo.y, hm, h2[1]);
        h2[2] = fmaf(alo.z, hm, h2[2]); h2[3] = fmaf(alo.w, hm, h2[3]);
        h2[4] = fmaf(ahi.x, hm, h2[4]); h2[5] = fmaf(ahi.y, hm, h2[5]);
        h2[6] = fmaf(ahi.z, hm, h2[6]); h2[7] = fmaf(ahi.w, hm, h2[7]);
    }
    const float b2j = b2s[j];
    #pragma unroll
    for (int n = 0; n < 8; n++) h2[n] = fmaxf(h2[n] + b2j, 0.0f);

    // ---- output: reduce over 32 columns, then relu + mean over nodes ----
    const float woj = Wouts[j];
    float s[8];
    #pragma unroll
    for (int n = 0; n < 8; n++) s[n] = h2[n] * woj;
    #pragma unroll
    for (int mask = 16; mask >= 1; mask >>= 1) {
        #pragma unroll
        for (int n = 0; n < 8; n++) s[n] += __shfl_xor(s[n], mask, 64);
    }
    if (j == 0) {
        float r = 0.0f;
        #pragma unroll
        for (int n = 0; n < 8; n++) r += fmaxf(s[n] + boutv, 0.0f);
        r *= 0.125f;
        long long gg = gbase + g;
        if (gg < B) out[gg] = r;
    }
}

extern "C" void kernel_launch(void* const* d_in, const int* in_sizes, int n_in,
                              void* d_out, int out_size, void* d_ws, size_t ws_size,
                              hipStream_t stream) {
    const float* x    = (const float*)d_in[0];
    const int*   ei   = (const int*)d_in[1];
    const float* W1   = (const float*)d_in[2];
    const float* b1   = (const float*)d_in[3];
    const float* W2   = (const float*)d_in[4];
    const float* b2   = (const float*)d_in[5];
    const float* Wout = (const float*)d_in[6];
    const float* bout = (const float*)d_in[7];
    float* out = (float*)d_out;

    const int B = in_sizes[0] / 24;           // 262144
    const int grid = (B + GPB - 1) / GPB;     // 32768 blocks
    gnn_kernel<<<grid, 256, 0, stream>>>(x, ei, W1, b1, W2, b2, Wout, bout, out, B);
}

// Round 3
// 74.984 us; speedup vs baseline: 2.4414x; 2.4414x over previous
//
#include <hip/hip_runtime.h>

// VanillaGNN via MFMA: B=262144 graphs, N=8 nodes, DIN=3, DH=32, DOUT=1.
// Per wave: 4 graphs = 32 node-rows.
//   h1 (VALU, lands in A-frag layout) -> t = h1@W2 (split-bf16, 6 MFMA)
//   -> shfl redistribute C->B-frag -> h2 = blockdiag(A)@t (6 MFMA)
//   -> bias/relu/Wout + LDS transpose + row reduce.
// mfma_f32_32x32x16_bf16 layouts (gfx950):
//   A: lane row=l&31, k=8*(l>>5)+j (per K-step)   B: col=l&31, same k
//   C/D: col=l&31, row=(reg&3)+8*(reg>>2)+4*(l>>5)

typedef __bf16 bf16x8 __attribute__((ext_vector_type(8)));
typedef float  f32x16 __attribute__((ext_vector_type(16)));

#define GPT 16  // graphs per block tile (4 waves x 4 graphs)

__global__ __launch_bounds__(256, 2) void gnn_kernel(
    const float* __restrict__ x,       // [B,8,3]
    const int* __restrict__ ei,        // [2,32] int32
    const float* __restrict__ W1,      // [3,32]
    const float* __restrict__ b1,      // [32]
    const float* __restrict__ W2,      // [32,32]
    const float* __restrict__ b2,      // [32]
    const float* __restrict__ Wout,    // [32]
    const float* __restrict__ bout,    // [1]
    float* __restrict__ out,           // [B]
    int B, int ntiles)
{
    __shared__ float As[64];           // A[n][m] (n=dst)
    __shared__ float degs[8], dinvs[8];
    __shared__ float W1s[96], b1s[32], W2s[1024], b2s[32], Wouts[32];
    __shared__ float xs[GPT * 24];     // [g][8][3]
    __shared__ float ts[4][32 * 36];   // per-wave transpose area (stride 36: 16B-aligned rows)

    const int tid = threadIdx.x;

    // ---- stage weights / build A (once per block) ----
    if (tid < 96) W1s[tid] = W1[tid];
    if (tid < 64) As[tid] = 0.0f;
    if (tid < 32) { b1s[tid] = b1[tid]; b2s[tid] = b2[tid]; Wouts[tid] = Wout[tid]; }
    if (tid < 8)  degs[tid] = 1.0f;
    for (int i = tid; i < 1024; i += 256) W2s[i] = W2[i];
    __syncthreads();
    if (tid < 32) { int d = ei[32 + tid]; atomicAdd(&degs[d], 1.0f); }
    __syncthreads();
    if (tid < 8) dinvs[tid] = 1.0f / sqrtf(degs[tid]);
    __syncthreads();
    if (tid < 32) {
        int s = ei[tid], d = ei[32 + tid];
        atomicAdd(&As[d * 8 + s], dinvs[s] * dinvs[d]);
    } else if (tid < 40) {
        int n = tid - 32;
        atomicAdd(&As[n * 8 + n], dinvs[n] * dinvs[n]);
    }
    __syncthreads();

    // ---- per-lane constants ----
    const int lane = tid & 63;
    const int wv   = tid >> 6;    // wave 0..3
    const int r    = lane & 31;   // node-row within wave tile
    const int q    = lane >> 5;   // k-half selector
    const int n8   = r & 7;       // node within graph
    const int gl   = r >> 3;      // graph within wave (0..3)
    const int c    = r;           // output column (C-layout col = lane&31)
    const int g    = wv * 4 + gl; // block-local graph

    float arow[8];
    #pragma unroll
    for (int m = 0; m < 8; m++) arow[m] = As[n8 * 8 + m];

    // layer-1 weights for my 16 h1 columns: cols = {8q+j} U {16+8q+j}
    float w1r0[16], w1r1[16], w1r2[16], b1r[16];
    #pragma unroll
    for (int j = 0; j < 16; j++) {
        int cc = (j < 8) ? (q * 8 + j) : (16 + q * 8 + (j - 8));
        w1r0[j] = W1s[cc]; w1r1[j] = W1s[32 + cc]; w1r2[j] = W1s[64 + cc];
        b1r[j] = b1s[cc];
    }

    // W2 B-frags (split): step s, elem j -> W2[s*16 + 8q + j][c]
    bf16x8 w2hi[2], w2lo[2];
    #pragma unroll
    for (int s = 0; s < 2; s++) {
        #pragma unroll
        for (int j = 0; j < 8; j++) {
            float v = W2s[(s * 16 + q * 8 + j) * 32 + c];
            __bf16 h = (__bf16)v;
            w2hi[s][j] = h;
            w2lo[s][j] = (__bf16)(v - (float)h);
        }
    }
    // A32 = blockdiag(A,A,A,A) A-frags (split): nonzero iff (2s+q)==gl
    bf16x8 a32hi[2], a32lo[2];
    #pragma unroll
    for (int s = 0; s < 2; s++) {
        bool mine = (2 * s + q) == gl;
        #pragma unroll
        for (int j = 0; j < 8; j++) {
            float v = mine ? arow[j] : 0.0f;
            __bf16 h = (__bf16)v;
            a32hi[s][j] = h;
            a32lo[s][j] = (__bf16)(v - (float)h);
        }
    }
    const float b2c = b2s[c], woutc = Wouts[c], boutv = bout[0];
    float* tw = &ts[wv][0];

    // ---- tile loop ----
    for (int tile = blockIdx.x; tile < ntiles; tile += gridDim.x) {
        const long long gbase = (long long)tile * GPT;
        __syncthreads();  // xs safe to overwrite
        if (tid < 96) {
            long long i4 = gbase * 6 + tid;
            if (i4 < (long long)B * 6)
                reinterpret_cast<float4*>(xs)[tid] = reinterpret_cast<const float4*>(x)[i4];
        }
        __syncthreads();

        // ---- layer 1: y = A@x (row r), h1 = relu(y@W1 + b1) in A-frag layout ----
        float xv[24];
        #pragma unroll
        for (int i = 0; i < 6; i++) {
            float4 v = reinterpret_cast<float4*>(&xs[g * 24])[i];
            xv[4 * i] = v.x; xv[4 * i + 1] = v.y; xv[4 * i + 2] = v.z; xv[4 * i + 3] = v.w;
        }
        float y0 = 0.f, y1 = 0.f, y2 = 0.f;
        #pragma unroll
        for (int m = 0; m < 8; m++) {
            y0 = fmaf(arow[m], xv[m * 3 + 0], y0);
            y1 = fmaf(arow[m], xv[m * 3 + 1], y1);
            y2 = fmaf(arow[m], xv[m * 3 + 2], y2);
        }
        float h1[16];
        #pragma unroll
        for (int j = 0; j < 16; j++)
            h1[j] = fmaxf(fmaf(y0, w1r0[j], fmaf(y1, w1r1[j], fmaf(y2, w1r2[j], b1r[j]))), 0.0f);

        bf16x8 ahi[2], alo[2];
        #pragma unroll
        for (int s = 0; s < 2; s++) {
            #pragma unroll
            for (int j = 0; j < 8; j++) {
                float v = h1[s * 8 + j];
                __bf16 h = (__bf16)v;
                ahi[s][j] = h;
                alo[s][j] = (__bf16)(v - (float)h);
            }
        }

        // ---- GEMM: t = h1 @ W2 (split-bf16, 2 K-steps x 3 products) ----
        f32x16 acc;
        #pragma unroll
        for (int k = 0; k < 16; k++) acc[k] = 0.0f;
        acc = __builtin_amdgcn_mfma_f32_32x32x16_bf16(ahi[0], w2hi[0], acc, 0, 0, 0);
        acc = __builtin_amdgcn_mfma_f32_32x32x16_bf16(ahi[0], w2lo[0], acc, 0, 0, 0);
        acc = __builtin_amdgcn_mfma_f32_32x32x16_bf16(alo[0], w2hi[0], acc, 0, 0, 0);
        acc = __builtin_amdgcn_mfma_f32_32x32x16_bf16(ahi[1], w2hi[1], acc, 0, 0, 0);
        acc = __builtin_amdgcn_mfma_f32_32x32x16_bf16(ahi[1], w2lo[1], acc, 0, 0, 0);
        acc = __builtin_amdgcn_mfma_f32_32x32x16_bf16(alo[1], w2hi[1], acc, 0, 0, 0);

        // ---- redistribute C-layout -> B-frag (rows of t become k) ----
        float got0[4], got1[4];
        #pragma unroll
        for (int i = 0; i < 4; i++) {
            float send = (q == 0) ? acc[4 + i] : acc[i];
            got0[i] = __shfl_xor(send, 32, 64);
        }
        #pragma unroll
        for (int i = 0; i < 4; i++) {
            float send = (q == 0) ? acc[12 + i] : acc[8 + i];
            got1[i] = __shfl_xor(send, 32, 64);
        }
        float bf[16];
        #pragma unroll
        for (int i = 0; i < 4; i++) {
            bf[i]      = (q == 0) ? acc[i]      : got0[i];
            bf[4 + i]  = (q == 0) ? got0[i]     : acc[4 + i];
            bf[8 + i]  = (q == 0) ? acc[8 + i]  : got1[i];
            bf[12 + i] = (q == 0) ? got1[i]     : acc[12 + i];
        }
        bf16x8 bhi[2], blo[2];
        #pragma unroll
        for (int s = 0; s < 2; s++) {
            #pragma unroll
            for (int j = 0; j < 8; j++) {
                float v = bf[s * 8 + j];
                __bf16 h = (__bf16)v;
                bhi[s][j] = h;
                blo[s][j] = (__bf16)(v - (float)h);
            }
        }

        // ---- aggregation: h2pre = A32 @ t ----
        f32x16 acc2;
        #pragma unroll
        for (int k = 0; k < 16; k++) acc2[k] = 0.0f;
        acc2 = __builtin_amdgcn_mfma_f32_32x32x16_bf16(a32hi[0], bhi[0], acc2, 0, 0, 0);
        acc2 = __builtin_amdgcn_mfma_f32_32x32x16_bf16(a32hi[0], blo[0], acc2, 0, 0, 0);
        acc2 = __builtin_amdgcn_mfma_f32_32x32x16_bf16(a32lo[0], bhi[0], acc2, 0, 0, 0);
        acc2 = __builtin_amdgcn_mfma_f32_32x32x16_bf16(a32hi[1], bhi[1], acc2, 0, 0, 0);
        acc2 = __builtin_amdgcn_mfma_f32_32x32x16_bf16(a32hi[1], blo[1], acc2, 0, 0, 0);
        acc2 = __builtin_amdgcn_mfma_f32_32x32x16_bf16(a32lo[1], bhi[1], acc2, 0, 0, 0);

        // ---- epilogue: relu(h2pre+b2)*Wout -> transpose -> row sums ----
        #pragma unroll
        for (int k = 0; k < 16; k++) {
            int row = (k & 3) + 8 * (k >> 2) + 4 * q;
            tw[row * 36 + c] = fmaxf(acc2[k] + b2c, 0.0f) * woutc;
        }
        float rs = 0.0f;
        #pragma unroll
        for (int i = 0; i < 4; i++) {
            float4 v = *reinterpret_cast<float4*>(&tw[r * 36 + q * 16 + i * 4]);
            rs += v.x + v.y + v.z + v.w;
        }
        rs += __shfl_xor(rs, 32, 64);                 // combine col halves
        float o = fmaxf(rs + boutv, 0.0f);            // relu per node-row
        o += __shfl_xor(o, 1, 64);
        o += __shfl_xor(o, 2, 64);
        o += __shfl_xor(o, 4, 64);                    // sum 8 nodes
        if (q == 0 && n8 == 0) {
            long long gg = gbase + g;
            if (gg < (long long)B) out[gg] = o * 0.125f;
        }
    }
}

extern "C" void kernel_launch(void* const* d_in, const int* in_sizes, int n_in,
                              void* d_out, int out_size, void* d_ws, size_t ws_size,
                              hipStream_t stream) {
    const float* x    = (const float*)d_in[0];
    const int*   ei   = (const int*)d_in[1];
    const float* W1   = (const float*)d_in[2];
    const float* b1   = (const float*)d_in[3];
    const float* W2   = (const float*)d_in[4];
    const float* b2   = (const float*)d_in[5];
    const float* Wout = (const float*)d_in[6];
    const float* bout = (const float*)d_in[7];
    float* out = (float*)d_out;
    (void)d_ws; (void)ws_size; (void)out_size; (void)n_in;

    const int B = in_sizes[0] / 24;                 // 262144
    const int ntiles = (B + GPT - 1) / GPT;         // 16384
    const int grid = ntiles < 2048 ? ntiles : 2048; // persistent-ish, grid-stride
    gnn_kernel<<<grid, 256, 0, stream>>>(x, ei, W1, b1, W2, b2, Wout, bout, out, B, ntiles);
}

// Round 4
// 57.445 us; speedup vs baseline: 3.1869x; 1.3053x over previous
//
#include <hip/hip_runtime.h>

// VanillaGNN via MFMA: B=262144 graphs, N=8 nodes, DIN=3, DH=32, DOUT=1.
// Per wave: 4 graphs = 32 node-rows.
//   h1 (VALU, lands in A-frag layout) -> t = h1@W2 (split-bf16, 6 MFMA, C-layout
//   lane=hidden) -> half-swap -> tT as A-frag -> h2T = tT @ A32T (6 MFMA,
//   B-operand = hoisted const A32 frags; blockdiag symmetry makes A32T B-frags
//   identical to A32 A-frags) -> h2T C-layout lane=node, regs=hidden ->
//   in-register Wout reduction (no LDS transpose).
// mfma_f32_32x32x16_bf16 layouts (gfx950):
//   A: lane row=l&31, k=s*16+8*(l>>5)+j   B: col=l&31, same k
//   C/D: col=l&31, row=(reg&3)+8*(reg>>2)+4*(l>>5)

typedef __bf16 bf16x8 __attribute__((ext_vector_type(8)));
typedef float  f32x16 __attribute__((ext_vector_type(16)));

#define GPT 16  // graphs per block tile (4 waves x 4 graphs)

__global__ __launch_bounds__(256, 2) void gnn_kernel(
    const float* __restrict__ x,       // [B,8,3]
    const int* __restrict__ ei,        // [2,32] int32
    const float* __restrict__ W1,      // [3,32]
    const float* __restrict__ b1,      // [32]
    const float* __restrict__ W2,      // [32,32]
    const float* __restrict__ b2,      // [32]
    const float* __restrict__ Wout,    // [32]
    const float* __restrict__ bout,    // [1]
    float* __restrict__ out,           // [B]
    int B, int ntiles)
{
    __shared__ float As[64];           // A[n][m] (n=dst)
    __shared__ float degs[8], dinvs[8];
    __shared__ float W1s[96], b1s[32], W2s[1024], b2s[32], Wouts[32];
    __shared__ float xs[2][GPT * 24];  // double-buffered [g][8][3]

    const int tid = threadIdx.x;

    // ---- stage weights / build A (once per block) ----
    if (tid < 96) W1s[tid] = W1[tid];
    if (tid < 64) As[tid] = 0.0f;
    if (tid < 32) { b1s[tid] = b1[tid]; b2s[tid] = b2[tid]; Wouts[tid] = Wout[tid]; }
    if (tid < 8)  degs[tid] = 1.0f;
    for (int i = tid; i < 1024; i += 256) W2s[i] = W2[i];
    __syncthreads();
    if (tid < 32) { int d = ei[32 + tid]; atomicAdd(&degs[d], 1.0f); }
    __syncthreads();
    if (tid < 8) dinvs[tid] = 1.0f / sqrtf(degs[tid]);
    __syncthreads();
    if (tid < 32) {
        int s = ei[tid], d = ei[32 + tid];
        atomicAdd(&As[d * 8 + s], dinvs[s] * dinvs[d]);
    } else if (tid < 40) {
        int n = tid - 32;
        atomicAdd(&As[n * 8 + n], dinvs[n] * dinvs[n]);
    }
    __syncthreads();

    // ---- per-lane constants ----
    const int lane = tid & 63;
    const int wv   = tid >> 6;    // wave 0..3
    const int r    = lane & 31;
    const int q    = lane >> 5;   // k-half / row-half selector
    const int n8   = r & 7;       // node within graph
    const int gl   = r >> 3;      // graph within wave
    const int g    = wv * 4 + gl; // block-local graph

    float arow[8];
    #pragma unroll
    for (int m = 0; m < 8; m++) arow[m] = As[n8 * 8 + m];

    // layer-1 weights for my 16 h1 columns: cols = {8q+j} U {16+8q+j}
    float w1r0[16], w1r1[16], w1r2[16], b1r[16];
    #pragma unroll
    for (int j = 0; j < 16; j++) {
        int cc = (j < 8) ? (q * 8 + j) : (16 + q * 8 + (j - 8));
        w1r0[j] = W1s[cc]; w1r1[j] = W1s[32 + cc]; w1r2[j] = W1s[64 + cc];
        b1r[j] = b1s[cc];
    }

    // W2 B-frags (split): step s, elem j -> W2[s*16 + 8q + j][c]
    bf16x8 w2hi[2], w2lo[2];
    #pragma unroll
    for (int s = 0; s < 2; s++) {
        #pragma unroll
        for (int j = 0; j < 8; j++) {
            float v = W2s[(s * 16 + q * 8 + j) * 32 + r];
            __bf16 h = (__bf16)v;
            w2hi[s][j] = h;
            w2lo[s][j] = (__bf16)(v - (float)h);
        }
    }
    // A32T B-frags (split): value at (k=s16+8q+j, col=r) = A32[r][k]
    //  = gate((2s+q)==gl) * A[n8][j]  — identical to the A32 A-frags.
    bf16x8 a32hi[2], a32lo[2];
    #pragma unroll
    for (int s = 0; s < 2; s++) {
        bool mine = (2 * s + q) == gl;
        #pragma unroll
        for (int j = 0; j < 8; j++) {
            float v = mine ? arow[j] : 0.0f;
            __bf16 h = (__bf16)v;
            a32hi[s][j] = h;
            a32lo[s][j] = (__bf16)(v - (float)h);
        }
    }
    // epilogue per-reg constants: reg k of h2T C-layout holds hidden row
    //   hk = (k&3) + 8*(k>>2) + 4q
    float b2r[16], woutr[16];
    #pragma unroll
    for (int k = 0; k < 16; k++) {
        int hk = (k & 3) + 8 * (k >> 2) + 4 * q;
        b2r[k] = b2s[hk]; woutr[k] = Wouts[hk];
    }
    const float boutv = bout[0];

    // ---- x prefetch (tile 0) ----
    const float4* x4 = reinterpret_cast<const float4*>(x);
    float4 nxt;
    if (tid < 96 && blockIdx.x < ntiles)
        nxt = x4[(long long)blockIdx.x * 96 + tid];
    int buf = 0;

    // ---- tile loop: 1 barrier per tile, x prefetched in regs ----
    for (int tile = blockIdx.x; tile < ntiles; tile += gridDim.x) {
        const long long gbase = (long long)tile * GPT;
        if (tid < 96) *reinterpret_cast<float4*>(&xs[buf][tid * 4]) = nxt;
        int tnext = tile + gridDim.x;
        if (tid < 96 && tnext < ntiles)
            nxt = x4[(long long)tnext * 96 + tid];
        __syncthreads();

        // ---- layer 1: y = A@x (row r), h1 = relu(y@W1+b1) in A-frag layout ----
        float xv[24];
        #pragma unroll
        for (int i = 0; i < 6; i++) {
            float4 v = *reinterpret_cast<float4*>(&xs[buf][g * 24 + i * 4]);
            xv[4 * i] = v.x; xv[4 * i + 1] = v.y; xv[4 * i + 2] = v.z; xv[4 * i + 3] = v.w;
        }
        float y0 = 0.f, y1 = 0.f, y2 = 0.f;
        #pragma unroll
        for (int m = 0; m < 8; m++) {
            y0 = fmaf(arow[m], xv[m * 3 + 0], y0);
            y1 = fmaf(arow[m], xv[m * 3 + 1], y1);
            y2 = fmaf(arow[m], xv[m * 3 + 2], y2);
        }
        float h1[16];
        #pragma unroll
        for (int j = 0; j < 16; j++)
            h1[j] = fmaxf(fmaf(y0, w1r0[j], fmaf(y1, w1r1[j], fmaf(y2, w1r2[j], b1r[j]))), 0.0f);

        bf16x8 ahi[2], alo[2];
        #pragma unroll
        for (int s = 0; s < 2; s++) {
            #pragma unroll
            for (int j = 0; j < 8; j++) {
                float v = h1[s * 8 + j];
                __bf16 h = (__bf16)v;
                ahi[s][j] = h;
                alo[s][j] = (__bf16)(v - (float)h);
            }
        }

        // ---- GEMM: t = h1 @ W2 (split-bf16) -> C-layout lane=hidden ----
        f32x16 acc;
        #pragma unroll
        for (int k = 0; k < 16; k++) acc[k] = 0.0f;
        acc = __builtin_amdgcn_mfma_f32_32x32x16_bf16(ahi[0], w2hi[0], acc, 0, 0, 0);
        acc = __builtin_amdgcn_mfma_f32_32x32x16_bf16(ahi[0], w2lo[0], acc, 0, 0, 0);
        acc = __builtin_amdgcn_mfma_f32_32x32x16_bf16(alo[0], w2hi[0], acc, 0, 0, 0);
        acc = __builtin_amdgcn_mfma_f32_32x32x16_bf16(ahi[1], w2hi[1], acc, 0, 0, 0);
        acc = __builtin_amdgcn_mfma_f32_32x32x16_bf16(ahi[1], w2lo[1], acc, 0, 0, 0);
        acc = __builtin_amdgcn_mfma_f32_32x32x16_bf16(alo[1], w2hi[1], acc, 0, 0, 0);

        // ---- half-swap: C-layout rows -> tT A-frag (k = node index) ----
        float fA0[8], fA1[8];
        #pragma unroll
        for (int i = 0; i < 4; i++) {
            float send0 = q ? acc[i] : acc[4 + i];
            float got0  = __shfl_xor(send0, 32, 64);
            fA0[i]     = q ? got0       : acc[i];
            fA0[4 + i] = q ? acc[4 + i] : got0;
            float send1 = q ? acc[8 + i] : acc[12 + i];
            float got1  = __shfl_xor(send1, 32, 64);
            fA1[i]     = q ? got1        : acc[8 + i];
            fA1[4 + i] = q ? acc[12 + i] : got1;
        }
        bf16x8 thi[2], tlo[2];
        #pragma unroll
        for (int j = 0; j < 8; j++) {
            float v0 = fA0[j];
            __bf16 h0 = (__bf16)v0;
            thi[0][j] = h0; tlo[0][j] = (__bf16)(v0 - (float)h0);
            float v1 = fA1[j];
            __bf16 h1v = (__bf16)v1;
            thi[1][j] = h1v; tlo[1][j] = (__bf16)(v1 - (float)h1v);
        }

        // ---- aggregation: h2T = tT @ A32T (+ b2 folded into acc init) ----
        f32x16 acc2;
        #pragma unroll
        for (int k = 0; k < 16; k++) acc2[k] = b2r[k];
        acc2 = __builtin_amdgcn_mfma_f32_32x32x16_bf16(thi[0], a32hi[0], acc2, 0, 0, 0);
        acc2 = __builtin_amdgcn_mfma_f32_32x32x16_bf16(thi[0], a32lo[0], acc2, 0, 0, 0);
        acc2 = __builtin_amdgcn_mfma_f32_32x32x16_bf16(tlo[0], a32hi[0], acc2, 0, 0, 0);
        acc2 = __builtin_amdgcn_mfma_f32_32x32x16_bf16(thi[1], a32hi[1], acc2, 0, 0, 0);
        acc2 = __builtin_amdgcn_mfma_f32_32x32x16_bf16(thi[1], a32lo[1], acc2, 0, 0, 0);
        acc2 = __builtin_amdgcn_mfma_f32_32x32x16_bf16(tlo[1], a32hi[1], acc2, 0, 0, 0);

        // ---- epilogue: lane=node, regs=hidden -> in-register reduction ----
        float ssum = 0.0f;
        #pragma unroll
        for (int k = 0; k < 16; k++)
            ssum = fmaf(fmaxf(acc2[k], 0.0f), woutr[k], ssum);
        ssum += __shfl_xor(ssum, 32, 64);          // other hidden half
        float o = fmaxf(ssum + boutv, 0.0f);       // relu per node
        o += __shfl_xor(o, 1, 64);
        o += __shfl_xor(o, 2, 64);
        o += __shfl_xor(o, 4, 64);                 // sum 8 nodes of my graph
        if (q == 0 && n8 == 0) {
            long long gg = gbase + g;
            if (gg < (long long)B) out[gg] = o * 0.125f;
        }
        buf ^= 1;
    }
}

extern "C" void kernel_launch(void* const* d_in, const int* in_sizes, int n_in,
                              void* d_out, int out_size, void* d_ws, size_t ws_size,
                              hipStream_t stream) {
    const float* x    = (const float*)d_in[0];
    const int*   ei   = (const int*)d_in[1];
    const float* W1   = (const float*)d_in[2];
    const float* b1   = (const float*)d_in[3];
    const float* W2   = (const float*)d_in[4];
    const float* b2   = (const float*)d_in[5];
    const float* Wout = (const float*)d_in[6];
    const float* bout = (const float*)d_in[7];
    float* out = (float*)d_out;
    (void)d_ws; (void)ws_size; (void)out_size; (void)n_in;

    const int B = in_sizes[0] / 24;                 // 262144
    const int ntiles = (B + GPT - 1) / GPT;         // 16384
    const int grid = ntiles < 2048 ? ntiles : 2048; // grid-stride, 8 iters/block
    gnn_kernel<<<grid, 256, 0, stream>>>(x, ei, W1, b1, W2, b2, Wout, bout, out, B, ntiles);
}